// Round 1
// baseline (694.311 us; speedup 1.0000x reference)
//
#include <hip/hip_runtime.h>

// ---------------------------------------------------------------------------
// 2-layer GCN: out = log_softmax( Anorm @ relu(Anorm @ (x@W1) + b1) @ W2 + b2 )
// Anorm = D^-1/2 (A + I) D^-1/2 with deg over destination nodes (incl. self loop)
// ---------------------------------------------------------------------------

constexpr int K1 = 128;  // inner dim for both layers (IN == HID == 128)

__global__ void k_init_deg(int* __restrict__ deg, int n) {
    int i = blockIdx.x * blockDim.x + threadIdx.x;
    if (i < n) deg[i] = 1;  // self loop
}

__global__ void k_count_deg(const int* __restrict__ dst, int e, int* __restrict__ deg) {
    int i = blockIdx.x * blockDim.x + threadIdx.x;
    int stride = gridDim.x * blockDim.x;
    for (; i < e; i += stride) atomicAdd(&deg[dst[i]], 1);
}

__global__ void k_dinv(const int* __restrict__ deg, float* __restrict__ dinv, int n) {
    int i = blockIdx.x * blockDim.x + threadIdx.x;
    if (i < n) dinv[i] = rsqrtf((float)deg[i]);
}

// C[n,K2] = act(A[n,K1]) @ W[K1,K2]   (bias added later in k_init_agg)
template <int K2, bool RELU>
__global__ __launch_bounds__(256) void k_gemm(const float* __restrict__ A,
                                              const float* __restrict__ W,
                                              float* __restrict__ C, int n) {
    constexpr int RPB = (256 / K2) * 4;  // rows per block (K2=128 -> 8, K2=64 -> 16)
    __shared__ float Ws[K1 * K2];
    __shared__ float Xs[RPB][K1];

    const int tid = threadIdx.x;
    const int row0 = blockIdx.x * RPB;

    for (int i = tid; i < K1 * K2; i += 256) Ws[i] = W[i];
    for (int i = tid; i < RPB * K1; i += 256) {
        int r = i / K1, k = i % K1;
        int gr = row0 + r;
        float v = (gr < n) ? A[(size_t)gr * K1 + k] : 0.f;
        if (RELU) v = fmaxf(v, 0.f);
        Xs[r][k] = v;
    }
    __syncthreads();

    const int col = tid % K2;
    const int rg = tid / K2;
    const int rbase = rg * 4;

    float acc[4] = {0.f, 0.f, 0.f, 0.f};
    for (int k4 = 0; k4 < K1 / 4; ++k4) {
        float4 xv[4];
#pragma unroll
        for (int j = 0; j < 4; ++j)
            xv[j] = *reinterpret_cast<const float4*>(&Xs[rbase + j][k4 * 4]);
#pragma unroll
        for (int kk = 0; kk < 4; ++kk) {
            float w = Ws[(k4 * 4 + kk) * K2 + col];
            acc[0] += (&xv[0].x)[kk] * w;
            acc[1] += (&xv[1].x)[kk] * w;
            acc[2] += (&xv[2].x)[kk] * w;
            acc[3] += (&xv[3].x)[kk] * w;
        }
    }
#pragma unroll
    for (int j = 0; j < 4; ++j) {
        int gr = row0 + rbase + j;
        if (gr < n) C[(size_t)gr * K2 + col] = acc[j];
    }
}

// agg[i][c] = b[c] + dinv[i]^2 * xw[i][c]   (bias + self-loop message)
template <int K2>
__global__ void k_init_agg(const float* __restrict__ xw, const float* __restrict__ dinv,
                           const float* __restrict__ b, float* __restrict__ agg, int n) {
    int i = blockIdx.x * blockDim.x + threadIdx.x;
    if (i < n * K2) {
        int r = i / K2, c = i % K2;
        float di = dinv[r];
        agg[i] = b[c] + di * di * xw[i];
    }
}

// one wave per edge: agg[dst] += dinv[src]*dinv[dst] * xw[src]
template <int K2>
__global__ void k_scatter(const int* __restrict__ src, const int* __restrict__ dst,
                          const float* __restrict__ dinv, const float* __restrict__ xw,
                          float* __restrict__ agg, int e) {
    int gtid = blockIdx.x * blockDim.x + threadIdx.x;
    int widx = gtid >> 6;
    int lane = gtid & 63;
    if (widx >= e) return;
    int s = src[widx], d = dst[widx];
    float nrm = dinv[s] * dinv[d];
    const float* xr = xw + (size_t)s * K2;
    float* ar = agg + (size_t)d * K2;
#pragma unroll
    for (int c = lane; c < K2; c += 64)
        unsafeAtomicAdd(&ar[c], nrm * xr[c]);
}

// one wave per row of 64: out = v - max - log(sum(exp(v - max)))
__global__ void k_logsoftmax(const float* __restrict__ agg, float* __restrict__ out, int n) {
    int gtid = blockIdx.x * blockDim.x + threadIdx.x;
    int r = gtid >> 6, lane = gtid & 63;
    if (r >= n) return;
    float v = agg[(size_t)r * 64 + lane];
    float m = v;
#pragma unroll
    for (int o = 32; o; o >>= 1) m = fmaxf(m, __shfl_xor(m, o));
    float ex = expf(v - m);
    float s = ex;
#pragma unroll
    for (int o = 32; o; o >>= 1) s += __shfl_xor(s, o);
    out[(size_t)r * 64 + lane] = v - m - logf(s);
}

extern "C" void kernel_launch(void* const* d_in, const int* in_sizes, int n_in,
                              void* d_out, int out_size, void* d_ws, size_t ws_size,
                              hipStream_t stream) {
    const float* x  = (const float*)d_in[0];
    const int*   ei = (const int*)d_in[1];
    const float* W1 = (const float*)d_in[2];
    const float* b1 = (const float*)d_in[3];
    const float* W2 = (const float*)d_in[4];
    const float* b2 = (const float*)d_in[5];

    const int n = in_sizes[0] / K1;   // 50000
    const int e = in_sizes[1] / 2;    // 800000
    const int* src = ei;              // edge_index[0]
    const int* dst = ei + e;          // edge_index[1]
    float* out = (float*)d_out;

    // workspace layout (all f32): buf0[n*128] | buf1[n*128] | deg[n] | dinv[n]
    float* buf0 = (float*)d_ws;                     // xw1, later hw2
    float* buf1 = buf0 + (size_t)n * 128;           // agg1, later agg2
    int*   deg  = (int*)(buf1 + (size_t)n * 128);
    float* dinv = (float*)(deg + n);

    const int B = 256;

    k_init_deg<<<(n + B - 1) / B, B, 0, stream>>>(deg, n);
    k_count_deg<<<1024, B, 0, stream>>>(dst, e, deg);
    k_dinv<<<(n + B - 1) / B, B, 0, stream>>>(deg, dinv, n);

    // layer 1: xw1 = x @ W1 ; agg1 = b1 + selfloop + scatter ; (relu fused into gemm2)
    k_gemm<128, false><<<(n + 7) / 8, B, 0, stream>>>(x, W1, buf0, n);
    k_init_agg<128><<<(n * 128 + B - 1) / B, B, 0, stream>>>(buf0, dinv, b1, buf1, n);
    k_scatter<128><<<(int)(((size_t)e * 64 + B - 1) / B), B, 0, stream>>>(src, dst, dinv, buf0, buf1, e);

    // layer 2: hw2 = relu(agg1) @ W2 ; agg2 = b2 + selfloop + scatter
    k_gemm<64, true><<<(n + 15) / 16, B, 0, stream>>>(buf1, W2, buf0, n);
    k_init_agg<64><<<(n * 64 + B - 1) / B, B, 0, stream>>>(buf0, dinv, b2, buf1, n);
    k_scatter<64><<<(int)(((size_t)e * 64 + B - 1) / B), B, 0, stream>>>(src, dst, dinv, buf0, buf1, e);

    k_logsoftmax<<<(n * 64 + B - 1) / B, B, 0, stream>>>(buf1, out, n);
}

// Round 2
// 487.314 us; speedup vs baseline: 1.4248x; 1.4248x over previous
//
#include <hip/hip_runtime.h>

// ---------------------------------------------------------------------------
// 2-layer GCN, CSR-gather formulation (no float atomics):
// out = log_softmax( Anorm @ relu(Anorm @ (x@W1) + b1) @ W2 + b2 )
// Anorm = D^-1/2 (A + I) D^-1/2, deg over destination nodes (incl. self loop)
// ---------------------------------------------------------------------------

constexpr int K1 = 128;

__global__ void k_init_deg(int* __restrict__ deg, int n) {
    int i = blockIdx.x * blockDim.x + threadIdx.x;
    if (i < n) deg[i] = 1;  // self loop
}

__global__ void k_count_deg(const int* __restrict__ dst, int e, int* __restrict__ deg) {
    int i = blockIdx.x * blockDim.x + threadIdx.x;
    int stride = gridDim.x * blockDim.x;
    for (; i < e; i += stride) atomicAdd(&deg[dst[i]], 1);
}

__global__ void k_dinv(const int* __restrict__ deg, float* __restrict__ dinv, int n) {
    int i = blockIdx.x * blockDim.x + threadIdx.x;
    if (i < n) dinv[i] = rsqrtf((float)deg[i]);
}

// single-block exclusive scan of (deg[i]-1) -> off[i], cur[i]
__global__ __launch_bounds__(1024) void k_scan(const int* __restrict__ deg,
                                               int* __restrict__ off,
                                               int* __restrict__ cur, int n) {
    __shared__ int partial[1024];
    const int tid = threadIdx.x;
    const int CH = (n + 1023) / 1024;
    const int base = tid * CH;
    const int end = (base + CH < n) ? base + CH : n;

    int s = 0;
    for (int i = base; i < end; ++i) s += deg[i] - 1;
    partial[tid] = s;
    __syncthreads();
    for (int o = 1; o < 1024; o <<= 1) {
        int v = (tid >= o) ? partial[tid - o] : 0;
        __syncthreads();
        partial[tid] += v;
        __syncthreads();
    }
    int run = (tid > 0) ? partial[tid - 1] : 0;
    for (int i = base; i < end; ++i) {
        off[i] = run;
        cur[i] = run;
        run += deg[i] - 1;
    }
}

// counting-sort placement: csr entries grouped by dst
__global__ void k_fill(const int* __restrict__ src, const int* __restrict__ dst,
                       const float* __restrict__ dinv, int* __restrict__ cur,
                       int* __restrict__ csr_src, float* __restrict__ csr_nrm, int e) {
    int i = blockIdx.x * blockDim.x + threadIdx.x;
    int stride = gridDim.x * blockDim.x;
    for (; i < e; i += stride) {
        int s = src[i], d = dst[i];
        int p = atomicAdd(&cur[d], 1);
        csr_src[p] = s;
        csr_nrm[p] = dinv[s] * dinv[d];
    }
}

// C[n,K2] = A[n,K1] @ W[K1,K2]   (bias handled in gather)
template <int K2>
__global__ __launch_bounds__(256) void k_gemm(const float* __restrict__ A,
                                              const float* __restrict__ W,
                                              float* __restrict__ C, int n) {
    constexpr int RPB = (256 / K2) * 4;
    __shared__ float Ws[K1 * K2];
    __shared__ float Xs[RPB][K1];

    const int tid = threadIdx.x;
    const int row0 = blockIdx.x * RPB;

    for (int i = tid; i < K1 * K2; i += 256) Ws[i] = W[i];
    for (int i = tid; i < RPB * K1; i += 256) {
        int r = i / K1, k = i % K1;
        int gr = row0 + r;
        Xs[r][k] = (gr < n) ? A[(size_t)gr * K1 + k] : 0.f;
    }
    __syncthreads();

    const int col = tid % K2;
    const int rbase = (tid / K2) * 4;

    float acc[4] = {0.f, 0.f, 0.f, 0.f};
    for (int k4 = 0; k4 < K1 / 4; ++k4) {
        float4 xv[4];
#pragma unroll
        for (int j = 0; j < 4; ++j)
            xv[j] = *reinterpret_cast<const float4*>(&Xs[rbase + j][k4 * 4]);
#pragma unroll
        for (int kk = 0; kk < 4; ++kk) {
            float w = Ws[(k4 * 4 + kk) * K2 + col];
            acc[0] += (&xv[0].x)[kk] * w;
            acc[1] += (&xv[1].x)[kk] * w;
            acc[2] += (&xv[2].x)[kk] * w;
            acc[3] += (&xv[3].x)[kk] * w;
        }
    }
#pragma unroll
    for (int j = 0; j < 4; ++j) {
        int gr = row0 + rbase + j;
        if (gr < n) C[(size_t)gr * K2 + col] = acc[j];
    }
}

// one wave per dst node; lane owns 2 contiguous columns (K2=128).
// agg[d] = relu( b + dinv[d]^2*xw[d] + sum_e nrm[e]*xw[src[e]] )
__global__ __launch_bounds__(256) void k_gather128(
    const int* __restrict__ off, const int* __restrict__ deg,
    const int* __restrict__ csr_src, const float* __restrict__ csr_nrm,
    const float* __restrict__ xw, const float* __restrict__ dinv,
    const float* __restrict__ b, float* __restrict__ agg, int n) {
    int wid = (blockIdx.x * blockDim.x + threadIdx.x) >> 6;
    int lane = threadIdx.x & 63;
    if (wid >= n) return;

    float di = dinv[wid];
    float2 sv = *reinterpret_cast<const float2*>(xw + (size_t)wid * 128 + lane * 2);
    float a0 = b[lane * 2]     + di * di * sv.x;
    float a1 = b[lane * 2 + 1] + di * di * sv.y;

    int s0 = off[wid];
    int cnt = deg[wid] - 1;
    for (int t = 0; t < cnt; ++t) {
        int s = csr_src[s0 + t];
        float nr = csr_nrm[s0 + t];
        float2 v = *reinterpret_cast<const float2*>(xw + (size_t)s * 128 + lane * 2);
        a0 += nr * v.x;
        a1 += nr * v.y;
    }
    float2 o;
    o.x = fmaxf(a0, 0.f);  // relu fused (layer-1 output feeds gemm2)
    o.y = fmaxf(a1, 0.f);
    *reinterpret_cast<float2*>(agg + (size_t)wid * 128 + lane * 2) = o;
}

// one wave per dst node; lane owns column `lane` (K2=64); log_softmax fused.
__global__ __launch_bounds__(256) void k_gather64_lsm(
    const int* __restrict__ off, const int* __restrict__ deg,
    const int* __restrict__ csr_src, const float* __restrict__ csr_nrm,
    const float* __restrict__ xw, const float* __restrict__ dinv,
    const float* __restrict__ b, float* __restrict__ out, int n) {
    int wid = (blockIdx.x * blockDim.x + threadIdx.x) >> 6;
    int lane = threadIdx.x & 63;
    if (wid >= n) return;

    float di = dinv[wid];
    float a = b[lane] + di * di * xw[(size_t)wid * 64 + lane];

    int s0 = off[wid];
    int cnt = deg[wid] - 1;
    for (int t = 0; t < cnt; ++t) {
        int s = csr_src[s0 + t];
        float nr = csr_nrm[s0 + t];
        a += nr * xw[(size_t)s * 64 + lane];
    }

    float m = a;
#pragma unroll
    for (int o = 32; o; o >>= 1) m = fmaxf(m, __shfl_xor(m, o));
    float ex = expf(a - m);
    float s = ex;
#pragma unroll
    for (int o = 32; o; o >>= 1) s += __shfl_xor(s, o);
    out[(size_t)wid * 64 + lane] = a - m - logf(s);
}

extern "C" void kernel_launch(void* const* d_in, const int* in_sizes, int n_in,
                              void* d_out, int out_size, void* d_ws, size_t ws_size,
                              hipStream_t stream) {
    const float* x  = (const float*)d_in[0];
    const int*   ei = (const int*)d_in[1];
    const float* W1 = (const float*)d_in[2];
    const float* b1 = (const float*)d_in[3];
    const float* W2 = (const float*)d_in[4];
    const float* b2 = (const float*)d_in[5];

    const int n = in_sizes[0] / K1;   // 50000
    const int e = in_sizes[1] / 2;    // 800000
    const int* src = ei;
    const int* dst = ei + e;
    float* out = (float*)d_out;

    // ws layout (f32/int32):
    // buf0[n*128] | buf1[n*128] | deg[n] | dinv[n] | off[n] | cur[n] | csr_src[e] | csr_nrm[e]
    float* buf0    = (float*)d_ws;
    float* buf1    = buf0 + (size_t)n * 128;
    int*   deg     = (int*)(buf1 + (size_t)n * 128);
    float* dinv    = (float*)(deg + n);
    int*   off     = (int*)(dinv + n);
    int*   cur     = off + n;
    int*   csr_src = cur + n;
    float* csr_nrm = (float*)(csr_src + e);

    const int B = 256;

    k_init_deg<<<(n + B - 1) / B, B, 0, stream>>>(deg, n);
    k_count_deg<<<1024, B, 0, stream>>>(dst, e, deg);
    k_dinv<<<(n + B - 1) / B, B, 0, stream>>>(deg, dinv, n);
    k_scan<<<1, 1024, 0, stream>>>(deg, off, cur, n);
    k_fill<<<1024, B, 0, stream>>>(src, dst, dinv, cur, csr_src, csr_nrm, e);

    // layer 1: xw1 = x @ W1 ; agg1 = relu(gather)  -> buf1
    k_gemm<128><<<(n + 7) / 8, B, 0, stream>>>(x, W1, buf0, n);
    k_gather128<<<(n + 3) / 4, B, 0, stream>>>(off, deg, csr_src, csr_nrm,
                                               buf0, dinv, b1, buf1, n);

    // layer 2: hw2 = agg1 @ W2 ; out = log_softmax(gather)
    k_gemm<64><<<(n + 15) / 16, B, 0, stream>>>(buf1, W2, buf0, n);
    k_gather64_lsm<<<(n + 3) / 4, B, 0, stream>>>(off, deg, csr_src, csr_nrm,
                                                  buf0, dinv, b2, out, n);
}

// Round 3
// 385.616 us; speedup vs baseline: 1.8005x; 1.2637x over previous
//
#include <hip/hip_runtime.h>

// ---------------------------------------------------------------------------
// 2-layer GCN, CSR-gather formulation (no float atomics):
// out = log_softmax( Anorm @ relu(Anorm @ (x@W1) + b1) @ W2 + b2 )
// Anorm = D^-1/2 (A + I) D^-1/2, deg over destination nodes (incl. self loop)
// ---------------------------------------------------------------------------

constexpr int K1 = 128;
constexpr int SCAN_B = 256;  // elements per scan block

__global__ void k_init_deg(int* __restrict__ deg, int n) {
    int i = blockIdx.x * blockDim.x + threadIdx.x;
    if (i < n) deg[i] = 1;  // self loop
}

__global__ void k_count_deg(const int* __restrict__ dst, int e, int* __restrict__ deg) {
    int i = blockIdx.x * blockDim.x + threadIdx.x;
    int stride = gridDim.x * blockDim.x;
    for (; i < e; i += stride) atomicAdd(&deg[dst[i]], 1);
}

// phase 1: per-block sum of (deg-1)
__global__ __launch_bounds__(SCAN_B) void k_scan_part(const int* __restrict__ deg,
                                                      int* __restrict__ blocksum, int n) {
    __shared__ int red[SCAN_B];
    int i = blockIdx.x * SCAN_B + threadIdx.x;
    int v = (i < n) ? deg[i] - 1 : 0;
    red[threadIdx.x] = v;
    __syncthreads();
    for (int o = SCAN_B / 2; o; o >>= 1) {
        if (threadIdx.x < o) red[threadIdx.x] += red[threadIdx.x + o];
        __syncthreads();
    }
    if (threadIdx.x == 0) blocksum[blockIdx.x] = red[0];
}

// phase 2: exclusive scan of block sums (single small block)
__global__ __launch_bounds__(1024) void k_scan_top(int* __restrict__ blocksum, int nb) {
    __shared__ int sh[1024];
    int t = threadIdx.x;
    int v = (t < nb) ? blocksum[t] : 0;
    sh[t] = v;
    __syncthreads();
    for (int o = 1; o < 1024; o <<= 1) {
        int u = (t >= o) ? sh[t - o] : 0;
        __syncthreads();
        sh[t] += u;
        __syncthreads();
    }
    if (t < nb) blocksum[t] = sh[t] - v;  // exclusive
}

// phase 3: per-block exclusive scan + block offset; also dinv = rsqrt(deg)
__global__ __launch_bounds__(SCAN_B) void k_scan_final(const int* __restrict__ deg,
                                                       const int* __restrict__ blocksum,
                                                       int* __restrict__ off,
                                                       int* __restrict__ cur,
                                                       float* __restrict__ dinv, int n) {
    __shared__ int sh[SCAN_B];
    int t = threadIdx.x;
    int i = blockIdx.x * SCAN_B + t;
    int d = (i < n) ? deg[i] : 1;
    int v = (i < n) ? d - 1 : 0;
    sh[t] = v;
    __syncthreads();
    for (int o = 1; o < SCAN_B; o <<= 1) {
        int u = (t >= o) ? sh[t - o] : 0;
        __syncthreads();
        sh[t] += u;
        __syncthreads();
    }
    if (i < n) {
        int excl = blocksum[blockIdx.x] + sh[t] - v;
        off[i] = excl;
        cur[i] = excl;
        dinv[i] = rsqrtf((float)d);
    }
}

// counting-sort placement: csr entries grouped by dst
__global__ void k_fill(const int* __restrict__ src, const int* __restrict__ dst,
                       const float* __restrict__ dinv, int* __restrict__ cur,
                       int* __restrict__ csr_src, float* __restrict__ csr_nrm, int e) {
    int i = blockIdx.x * blockDim.x + threadIdx.x;
    int stride = gridDim.x * blockDim.x;
    for (; i < e; i += stride) {
        int s = src[i], d = dst[i];
        int p = atomicAdd(&cur[d], 1);
        csr_src[p] = s;
        csr_nrm[p] = dinv[s] * dinv[d];
    }
}

// C[n,K2] = A[n,K1] @ W[K1,K2]   (bias handled in gather)
template <int K2>
__global__ __launch_bounds__(256) void k_gemm(const float* __restrict__ A,
                                              const float* __restrict__ W,
                                              float* __restrict__ C, int n) {
    constexpr int RPB = (256 / K2) * 4;
    __shared__ float Ws[K1 * K2];
    __shared__ float Xs[RPB][K1];

    const int tid = threadIdx.x;
    const int row0 = blockIdx.x * RPB;

    for (int i = tid; i < K1 * K2; i += 256) Ws[i] = W[i];
    for (int i = tid; i < RPB * K1; i += 256) {
        int r = i / K1, k = i % K1;
        int gr = row0 + r;
        Xs[r][k] = (gr < n) ? A[(size_t)gr * K1 + k] : 0.f;
    }
    __syncthreads();

    const int col = tid % K2;
    const int rbase = (tid / K2) * 4;

    float acc[4] = {0.f, 0.f, 0.f, 0.f};
    for (int k4 = 0; k4 < K1 / 4; ++k4) {
        float4 xv[4];
#pragma unroll
        for (int j = 0; j < 4; ++j)
            xv[j] = *reinterpret_cast<const float4*>(&Xs[rbase + j][k4 * 4]);
#pragma unroll
        for (int kk = 0; kk < 4; ++kk) {
            float w = Ws[(k4 * 4 + kk) * K2 + col];
            acc[0] += (&xv[0].x)[kk] * w;
            acc[1] += (&xv[1].x)[kk] * w;
            acc[2] += (&xv[2].x)[kk] * w;
            acc[3] += (&xv[3].x)[kk] * w;
        }
    }
#pragma unroll
    for (int j = 0; j < 4; ++j) {
        int gr = row0 + rbase + j;
        if (gr < n) C[(size_t)gr * K2 + col] = acc[j];
    }
}

// one wave per dst node; lane owns 2 contiguous columns (K2=128).
__global__ __launch_bounds__(256) void k_gather128(
    const int* __restrict__ off, const int* __restrict__ deg,
    const int* __restrict__ csr_src, const float* __restrict__ csr_nrm,
    const float* __restrict__ xw, const float* __restrict__ dinv,
    const float* __restrict__ b, float* __restrict__ agg, int n) {
    int wid = (blockIdx.x * blockDim.x + threadIdx.x) >> 6;
    int lane = threadIdx.x & 63;
    if (wid >= n) return;

    float di = dinv[wid];
    float2 sv = *reinterpret_cast<const float2*>(xw + (size_t)wid * 128 + lane * 2);
    float a0 = b[lane * 2]     + di * di * sv.x;
    float a1 = b[lane * 2 + 1] + di * di * sv.y;

    int s0 = off[wid];
    int cnt = deg[wid] - 1;
    for (int t = 0; t < cnt; ++t) {
        int s = csr_src[s0 + t];
        float nr = csr_nrm[s0 + t];
        float2 v = *reinterpret_cast<const float2*>(xw + (size_t)s * 128 + lane * 2);
        a0 += nr * v.x;
        a1 += nr * v.y;
    }
    float2 o;
    o.x = fmaxf(a0, 0.f);  // relu fused (layer-1 output feeds gemm2)
    o.y = fmaxf(a1, 0.f);
    *reinterpret_cast<float2*>(agg + (size_t)wid * 128 + lane * 2) = o;
}

// one wave per dst node; lane owns column `lane` (K2=64); log_softmax fused.
__global__ __launch_bounds__(256) void k_gather64_lsm(
    const int* __restrict__ off, const int* __restrict__ deg,
    const int* __restrict__ csr_src, const float* __restrict__ csr_nrm,
    const float* __restrict__ xw, const float* __restrict__ dinv,
    const float* __restrict__ b, float* __restrict__ out, int n) {
    int wid = (blockIdx.x * blockDim.x + threadIdx.x) >> 6;
    int lane = threadIdx.x & 63;
    if (wid >= n) return;

    float di = dinv[wid];
    float a = b[lane] + di * di * xw[(size_t)wid * 64 + lane];

    int s0 = off[wid];
    int cnt = deg[wid] - 1;
    for (int t = 0; t < cnt; ++t) {
        int s = csr_src[s0 + t];
        float nr = csr_nrm[s0 + t];
        a += nr * xw[(size_t)s * 64 + lane];
    }

    float m = a;
#pragma unroll
    for (int o = 32; o; o >>= 1) m = fmaxf(m, __shfl_xor(m, o));
    float ex = expf(a - m);
    float s = ex;
#pragma unroll
    for (int o = 32; o; o >>= 1) s += __shfl_xor(s, o);
    out[(size_t)wid * 64 + lane] = a - m - logf(s);
}

extern "C" void kernel_launch(void* const* d_in, const int* in_sizes, int n_in,
                              void* d_out, int out_size, void* d_ws, size_t ws_size,
                              hipStream_t stream) {
    const float* x  = (const float*)d_in[0];
    const int*   ei = (const int*)d_in[1];
    const float* W1 = (const float*)d_in[2];
    const float* b1 = (const float*)d_in[3];
    const float* W2 = (const float*)d_in[4];
    const float* b2 = (const float*)d_in[5];

    const int n = in_sizes[0] / K1;   // 50000
    const int e = in_sizes[1] / 2;    // 800000
    const int* src = ei;
    const int* dst = ei + e;
    float* out = (float*)d_out;

    const int nb_scan = (n + SCAN_B - 1) / SCAN_B;  // 196 for n=50000 (must be <=1024)

    // ws layout (f32/int32):
    // buf0[n*128] | buf1[n*128] | deg[n] | dinv[n] | off[n] | cur[n] |
    // blocksum[nb_scan] | csr_src[e] | csr_nrm[e]
    float* buf0     = (float*)d_ws;
    float* buf1     = buf0 + (size_t)n * 128;
    int*   deg      = (int*)(buf1 + (size_t)n * 128);
    float* dinv     = (float*)(deg + n);
    int*   off      = (int*)(dinv + n);
    int*   cur      = off + n;
    int*   blocksum = cur + n;
    int*   csr_src  = blocksum + nb_scan;
    float* csr_nrm  = (float*)(csr_src + e);

    const int B = 256;

    k_init_deg<<<(n + B - 1) / B, B, 0, stream>>>(deg, n);
    k_count_deg<<<1024, B, 0, stream>>>(dst, e, deg);
    k_scan_part<<<nb_scan, SCAN_B, 0, stream>>>(deg, blocksum, n);
    k_scan_top<<<1, 1024, 0, stream>>>(blocksum, nb_scan);
    k_scan_final<<<nb_scan, SCAN_B, 0, stream>>>(deg, blocksum, off, cur, dinv, n);
    k_fill<<<1024, B, 0, stream>>>(src, dst, dinv, cur, csr_src, csr_nrm, e);

    // layer 1: xw1 = x @ W1 ; agg1 = relu(gather)  -> buf1
    k_gemm<128><<<(n + 7) / 8, B, 0, stream>>>(x, W1, buf0, n);
    k_gather128<<<(n + 3) / 4, B, 0, stream>>>(off, deg, csr_src, csr_nrm,
                                               buf0, dinv, b1, buf1, n);

    // layer 2: hw2 = agg1 @ W2 ; out = log_softmax(gather)
    k_gemm<64><<<(n + 15) / 16, B, 0, stream>>>(buf1, W2, buf0, n);
    k_gather64_lsm<<<(n + 3) / 4, B, 0, stream>>>(off, deg, csr_src, csr_nrm,
                                                  buf0, dinv, b2, out, n);
}

// Round 4
// 328.948 us; speedup vs baseline: 2.1107x; 1.1723x over previous
//
#include <hip/hip_runtime.h>

// ---------------------------------------------------------------------------
// 2-layer GCN, CSR-gather formulation (no float atomics):
// out = log_softmax( Anorm @ relu(Anorm @ (x@W1) + b1) @ W2 + b2 )
// Anorm = D^-1/2 (A + I) D^-1/2, deg over destination nodes (incl. self loop)
// ---------------------------------------------------------------------------

constexpr int K1 = 128;
constexpr int SCAN_B = 256;  // elements per scan block

__global__ void k_init_deg(int* __restrict__ deg, int n) {
    int i = blockIdx.x * blockDim.x + threadIdx.x;
    if (i < n) deg[i] = 1;  // self loop
}

__global__ void k_count_deg(const int* __restrict__ dst, int e, int* __restrict__ deg) {
    int i = blockIdx.x * blockDim.x + threadIdx.x;
    int stride = gridDim.x * blockDim.x;
    for (; i < e; i += stride) atomicAdd(&deg[dst[i]], 1);
}

// phase 1: per-block sum of (deg-1)
__global__ __launch_bounds__(SCAN_B) void k_scan_part(const int* __restrict__ deg,
                                                      int* __restrict__ blocksum, int n) {
    __shared__ int red[SCAN_B];
    int i = blockIdx.x * SCAN_B + threadIdx.x;
    int v = (i < n) ? deg[i] - 1 : 0;
    red[threadIdx.x] = v;
    __syncthreads();
    for (int o = SCAN_B / 2; o; o >>= 1) {
        if (threadIdx.x < o) red[threadIdx.x] += red[threadIdx.x + o];
        __syncthreads();
    }
    if (threadIdx.x == 0) blocksum[blockIdx.x] = red[0];
}

// phase 2: exclusive scan of block sums (single small block)
__global__ __launch_bounds__(1024) void k_scan_top(int* __restrict__ blocksum, int nb) {
    __shared__ int sh[1024];
    int t = threadIdx.x;
    int v = (t < nb) ? blocksum[t] : 0;
    sh[t] = v;
    __syncthreads();
    for (int o = 1; o < 1024; o <<= 1) {
        int u = (t >= o) ? sh[t - o] : 0;
        __syncthreads();
        sh[t] += u;
        __syncthreads();
    }
    if (t < nb) blocksum[t] = sh[t] - v;  // exclusive
}

// phase 3: per-block exclusive scan + block offset; also dinv = rsqrt(deg)
__global__ __launch_bounds__(SCAN_B) void k_scan_final(const int* __restrict__ deg,
                                                       const int* __restrict__ blocksum,
                                                       int* __restrict__ off,
                                                       int* __restrict__ cur,
                                                       float* __restrict__ dinv, int n) {
    __shared__ int sh[SCAN_B];
    int t = threadIdx.x;
    int i = blockIdx.x * SCAN_B + t;
    int d = (i < n) ? deg[i] : 1;
    int v = (i < n) ? d - 1 : 0;
    sh[t] = v;
    __syncthreads();
    for (int o = 1; o < SCAN_B; o <<= 1) {
        int u = (t >= o) ? sh[t - o] : 0;
        __syncthreads();
        sh[t] += u;
        __syncthreads();
    }
    if (i < n) {
        int excl = blocksum[blockIdx.x] + sh[t] - v;
        off[i] = excl;
        cur[i] = excl;
        dinv[i] = rsqrtf((float)d);
    }
}

// counting-sort placement: csr entries grouped by dst
__global__ void k_fill(const int* __restrict__ src, const int* __restrict__ dst,
                       const float* __restrict__ dinv, int* __restrict__ cur,
                       int* __restrict__ csr_src, float* __restrict__ csr_nrm, int e) {
    int i = blockIdx.x * blockDim.x + threadIdx.x;
    int stride = gridDim.x * blockDim.x;
    for (; i < e; i += stride) {
        int s = src[i], d = dst[i];
        int p = atomicAdd(&cur[d], 1);
        csr_src[p] = s;
        csr_nrm[p] = dinv[s] * dinv[d];
    }
}

// ---------------------------------------------------------------------------
// Register-blocked GEMM: C[n,K2] = A[n,128] @ W[128,K2]
// BM=64 rows/block, 256 threads. A transposed in LDS (As[k][m], pad 68).
// W staged in 4 k-phases of 32 rows. Micro-tile: K2=128 -> 8x4, K2=64 -> 4x4.
// ---------------------------------------------------------------------------
template <int K2>
__global__ __launch_bounds__(256) void k_gemm(const float* __restrict__ A,
                                              const float* __restrict__ W,
                                              float* __restrict__ C, int n) {
    constexpr int BM = 64;
    constexpr int APAD = 68;                 // 68*4 B = 272 B, keeps 16B alignment
    constexpr int RT = (K2 == 128) ? 8 : 4;  // rows per thread
    __shared__ float As[128 * APAD];         // 34.8 KB
    __shared__ float Ws[32 * K2];            // 16 KB (K2=128) / 8 KB (K2=64)

    const int tid = threadIdx.x;
    const int row0 = blockIdx.x * BM;

    // stage A transposed: thread handles row r = tid>>2, k-quads (tid&3)+4j
    {
        int r = tid >> 2;
        int gr = row0 + r;
        const float* Ar = A + (size_t)gr * 128;
        bool ok = gr < n;
#pragma unroll
        for (int j = 0; j < 8; ++j) {
            int q = (tid & 3) + 4 * j;  // k-quad 0..31
            float4 v = ok ? *reinterpret_cast<const float4*>(Ar + 4 * q)
                          : float4{0.f, 0.f, 0.f, 0.f};
            As[(4 * q + 0) * APAD + r] = v.x;
            As[(4 * q + 1) * APAD + r] = v.y;
            As[(4 * q + 2) * APAD + r] = v.z;
            As[(4 * q + 3) * APAD + r] = v.w;
        }
    }

    const int a = (K2 == 128) ? (tid & 7) : (tid & 15);
    const int r0 = 4 * a;  // K2=128: rows r0..r0+3 and r0+32..r0+35; K2=64: r0..r0+3
    const int c0 = (K2 == 128) ? ((tid >> 3) * 4) : ((tid >> 4) * 4);

    float acc[RT][4];
#pragma unroll
    for (int i = 0; i < RT; ++i)
#pragma unroll
        for (int j = 0; j < 4; ++j) acc[i][j] = 0.f;

    for (int p = 0; p < 4; ++p) {
        __syncthreads();  // phase 0: also covers A staging
        for (int i = tid; i < 32 * K2 / 4; i += 256) {
            *reinterpret_cast<float4*>(&Ws[i * 4]) =
                *reinterpret_cast<const float4*>(&W[(size_t)p * 32 * K2 + (size_t)i * 4]);
        }
        __syncthreads();

#pragma unroll 4
        for (int kk = 0; kk < 32; ++kk) {
            const float* as = &As[(p * 32 + kk) * APAD];
            float4 av0 = *reinterpret_cast<const float4*>(as + r0);
            float4 wv = *reinterpret_cast<const float4*>(&Ws[kk * K2 + c0]);
            if (K2 == 128) {
                float4 av1 = *reinterpret_cast<const float4*>(as + r0 + 32);
#pragma unroll
                for (int j = 0; j < 4; ++j) {
                    float w = (&wv.x)[j];
                    acc[0][j] += av0.x * w;
                    acc[1][j] += av0.y * w;
                    acc[2][j] += av0.z * w;
                    acc[3][j] += av0.w * w;
                    acc[RT - 4][j] += av1.x * w;   // RT==8 here
                    acc[RT - 3][j] += av1.y * w;
                    acc[RT - 2][j] += av1.z * w;
                    acc[RT - 1][j] += av1.w * w;
                }
            } else {
#pragma unroll
                for (int j = 0; j < 4; ++j) {
                    float w = (&wv.x)[j];
                    acc[0][j] += av0.x * w;
                    acc[1][j] += av0.y * w;
                    acc[2][j] += av0.z * w;
                    acc[3][j] += av0.w * w;
                }
            }
        }
    }

#pragma unroll
    for (int i = 0; i < RT; ++i) {
        int rr = (i < 4) ? (r0 + i) : (r0 + 32 + (i - 4));
        int gr = row0 + rr;
        if (gr < n) {
            float4 o;
            o.x = acc[i][0]; o.y = acc[i][1]; o.z = acc[i][2]; o.w = acc[i][3];
            *reinterpret_cast<float4*>(&C[(size_t)gr * K2 + c0]) = o;
        }
    }
}

// one wave per dst node; lane owns 2 contiguous columns (K2=128).
__global__ __launch_bounds__(256) void k_gather128(
    const int* __restrict__ off, const int* __restrict__ deg,
    const int* __restrict__ csr_src, const float* __restrict__ csr_nrm,
    const float* __restrict__ xw, const float* __restrict__ dinv,
    const float* __restrict__ b, float* __restrict__ agg, int n) {
    int wid = (blockIdx.x * blockDim.x + threadIdx.x) >> 6;
    int lane = threadIdx.x & 63;
    if (wid >= n) return;

    float di = dinv[wid];
    float2 sv = *reinterpret_cast<const float2*>(xw + (size_t)wid * 128 + lane * 2);
    float a0 = b[lane * 2]     + di * di * sv.x;
    float a1 = b[lane * 2 + 1] + di * di * sv.y;

    int s0 = off[wid];
    int cnt = deg[wid] - 1;
    for (int t = 0; t < cnt; ++t) {
        int s = csr_src[s0 + t];
        float nr = csr_nrm[s0 + t];
        float2 v = *reinterpret_cast<const float2*>(xw + (size_t)s * 128 + lane * 2);
        a0 += nr * v.x;
        a1 += nr * v.y;
    }
    float2 o;
    o.x = fmaxf(a0, 0.f);  // relu fused (layer-1 output feeds gemm2)
    o.y = fmaxf(a1, 0.f);
    *reinterpret_cast<float2*>(agg + (size_t)wid * 128 + lane * 2) = o;
}

// one wave per dst node; lane owns column `lane` (K2=64); log_softmax fused.
__global__ __launch_bounds__(256) void k_gather64_lsm(
    const int* __restrict__ off, const int* __restrict__ deg,
    const int* __restrict__ csr_src, const float* __restrict__ csr_nrm,
    const float* __restrict__ xw, const float* __restrict__ dinv,
    const float* __restrict__ b, float* __restrict__ out, int n) {
    int wid = (blockIdx.x * blockDim.x + threadIdx.x) >> 6;
    int lane = threadIdx.x & 63;
    if (wid >= n) return;

    float di = dinv[wid];
    float a = b[lane] + di * di * xw[(size_t)wid * 64 + lane];

    int s0 = off[wid];
    int cnt = deg[wid] - 1;
    for (int t = 0; t < cnt; ++t) {
        int s = csr_src[s0 + t];
        float nr = csr_nrm[s0 + t];
        a += nr * xw[(size_t)s * 64 + lane];
    }

    float m = a;
#pragma unroll
    for (int o = 32; o; o >>= 1) m = fmaxf(m, __shfl_xor(m, o));
    float ex = expf(a - m);
    float s = ex;
#pragma unroll
    for (int o = 32; o; o >>= 1) s += __shfl_xor(s, o);
    out[(size_t)wid * 64 + lane] = a - m - logf(s);
}

extern "C" void kernel_launch(void* const* d_in, const int* in_sizes, int n_in,
                              void* d_out, int out_size, void* d_ws, size_t ws_size,
                              hipStream_t stream) {
    const float* x  = (const float*)d_in[0];
    const int*   ei = (const int*)d_in[1];
    const float* W1 = (const float*)d_in[2];
    const float* b1 = (const float*)d_in[3];
    const float* W2 = (const float*)d_in[4];
    const float* b2 = (const float*)d_in[5];

    const int n = in_sizes[0] / K1;   // 50000
    const int e = in_sizes[1] / 2;    // 800000
    const int* src = ei;
    const int* dst = ei + e;
    float* out = (float*)d_out;

    const int nb_scan = (n + SCAN_B - 1) / SCAN_B;  // 196 for n=50000 (<=1024)

    // ws layout (f32/int32):
    // buf0[n*128] | buf1[n*128] | deg[n] | dinv[n] | off[n] | cur[n] |
    // blocksum[nb_scan] | csr_src[e] | csr_nrm[e]
    float* buf0     = (float*)d_ws;
    float* buf1     = buf0 + (size_t)n * 128;
    int*   deg      = (int*)(buf1 + (size_t)n * 128);
    float* dinv     = (float*)(deg + n);
    int*   off      = (int*)(dinv + n);
    int*   cur      = off + n;
    int*   blocksum = cur + n;
    int*   csr_src  = blocksum + nb_scan;
    float* csr_nrm  = (float*)(csr_src + e);

    const int B = 256;

    k_init_deg<<<(n + B - 1) / B, B, 0, stream>>>(deg, n);
    k_count_deg<<<1024, B, 0, stream>>>(dst, e, deg);
    k_scan_part<<<nb_scan, SCAN_B, 0, stream>>>(deg, blocksum, n);
    k_scan_top<<<1, 1024, 0, stream>>>(blocksum, nb_scan);
    k_scan_final<<<nb_scan, SCAN_B, 0, stream>>>(deg, blocksum, off, cur, dinv, n);
    k_fill<<<1024, B, 0, stream>>>(src, dst, dinv, cur, csr_src, csr_nrm, e);

    // layer 1: xw1 = x @ W1 ; agg1 = relu(gather)  -> buf1
    k_gemm<128><<<(n + 63) / 64, B, 0, stream>>>(x, W1, buf0, n);
    k_gather128<<<(n + 3) / 4, B, 0, stream>>>(off, deg, csr_src, csr_nrm,
                                               buf0, dinv, b1, buf1, n);

    // layer 2: hw2 = agg1 @ W2 ; out = log_softmax(gather)
    k_gemm<64><<<(n + 63) / 64, B, 0, stream>>>(buf1, W2, buf0, n);
    k_gather64_lsm<<<(n + 3) / 4, B, 0, stream>>>(off, deg, csr_src, csr_nrm,
                                                  buf0, dinv, b2, out, n);
}

// Round 5
// 245.431 us; speedup vs baseline: 2.8289x; 1.3403x over previous
//
#include <hip/hip_runtime.h>

// ---------------------------------------------------------------------------
// 2-layer GCN, CSR-gather formulation (no float atomics):
// out = log_softmax( Anorm @ relu(Anorm @ (x@W1) + b1) @ W2 + b2 )
// Anorm = D^-1/2 (A + I) D^-1/2, deg over destination nodes (incl. self loop)
// ---------------------------------------------------------------------------

constexpr int K1 = 128;
constexpr int SCAN_B = 256;  // elements per scan block

__global__ void k_init_deg(int* __restrict__ deg, int n) {
    int i = blockIdx.x * blockDim.x + threadIdx.x;
    if (i < n) deg[i] = 1;  // self loop
}

__global__ void k_count_deg(const int* __restrict__ dst, int e, int* __restrict__ deg) {
    int i = blockIdx.x * blockDim.x + threadIdx.x;
    int stride = gridDim.x * blockDim.x;
    for (; i < e; i += stride) atomicAdd(&deg[dst[i]], 1);
}

// phase 1: per-block sum of (deg-1)
__global__ __launch_bounds__(SCAN_B) void k_scan_part(const int* __restrict__ deg,
                                                      int* __restrict__ blocksum, int n) {
    __shared__ int red[SCAN_B];
    int i = blockIdx.x * SCAN_B + threadIdx.x;
    int v = (i < n) ? deg[i] - 1 : 0;
    red[threadIdx.x] = v;
    __syncthreads();
    for (int o = SCAN_B / 2; o; o >>= 1) {
        if (threadIdx.x < o) red[threadIdx.x] += red[threadIdx.x + o];
        __syncthreads();
    }
    if (threadIdx.x == 0) blocksum[blockIdx.x] = red[0];
}

// phase 2: exclusive scan of block sums (single small block)
__global__ __launch_bounds__(1024) void k_scan_top(int* __restrict__ blocksum, int nb) {
    __shared__ int sh[1024];
    int t = threadIdx.x;
    int v = (t < nb) ? blocksum[t] : 0;
    sh[t] = v;
    __syncthreads();
    for (int o = 1; o < 1024; o <<= 1) {
        int u = (t >= o) ? sh[t - o] : 0;
        __syncthreads();
        sh[t] += u;
        __syncthreads();
    }
    if (t < nb) blocksum[t] = sh[t] - v;  // exclusive
}

// phase 3: per-block exclusive scan + block offset; also dinv = rsqrt(deg)
__global__ __launch_bounds__(SCAN_B) void k_scan_final(const int* __restrict__ deg,
                                                       const int* __restrict__ blocksum,
                                                       int* __restrict__ off,
                                                       int* __restrict__ cur,
                                                       float* __restrict__ dinv, int n) {
    __shared__ int sh[SCAN_B];
    int t = threadIdx.x;
    int i = blockIdx.x * SCAN_B + t;
    int d = (i < n) ? deg[i] : 1;
    int v = (i < n) ? d - 1 : 0;
    sh[t] = v;
    __syncthreads();
    for (int o = 1; o < SCAN_B; o <<= 1) {
        int u = (t >= o) ? sh[t - o] : 0;
        __syncthreads();
        sh[t] += u;
        __syncthreads();
    }
    if (i < n) {
        int excl = blocksum[blockIdx.x] + sh[t] - v;
        off[i] = excl;
        cur[i] = excl;
        dinv[i] = rsqrtf((float)d);
    }
}

// counting-sort placement: interleaved csr entries {src, nrm} grouped by dst
__global__ void k_fill(const int* __restrict__ src, const int* __restrict__ dst,
                       const float* __restrict__ dinv, int* __restrict__ cur,
                       uint2* __restrict__ csr, int e) {
    int i = blockIdx.x * blockDim.x + threadIdx.x;
    int stride = gridDim.x * blockDim.x;
    for (; i < e; i += stride) {
        int s = src[i], d = dst[i];
        int p = atomicAdd(&cur[d], 1);
        uint2 ent;
        ent.x = (unsigned)s;
        ent.y = __float_as_uint(dinv[s] * dinv[d]);
        csr[p] = ent;
    }
}

// ---------------------------------------------------------------------------
// Register-blocked GEMM: C[n,K2] = A[n,128] @ W[128,K2]
// ---------------------------------------------------------------------------
template <int K2>
__global__ __launch_bounds__(256) void k_gemm(const float* __restrict__ A,
                                              const float* __restrict__ W,
                                              float* __restrict__ C, int n) {
    constexpr int BM = 64;
    constexpr int APAD = 68;
    constexpr int RT = (K2 == 128) ? 8 : 4;
    __shared__ float As[128 * APAD];
    __shared__ float Ws[32 * K2];

    const int tid = threadIdx.x;
    const int row0 = blockIdx.x * BM;

    {
        int r = tid >> 2;
        int gr = row0 + r;
        const float* Ar = A + (size_t)gr * 128;
        bool ok = gr < n;
#pragma unroll
        for (int j = 0; j < 8; ++j) {
            int q = (tid & 3) + 4 * j;
            float4 v = ok ? *reinterpret_cast<const float4*>(Ar + 4 * q)
                          : float4{0.f, 0.f, 0.f, 0.f};
            As[(4 * q + 0) * APAD + r] = v.x;
            As[(4 * q + 1) * APAD + r] = v.y;
            As[(4 * q + 2) * APAD + r] = v.z;
            As[(4 * q + 3) * APAD + r] = v.w;
        }
    }

    const int a = (K2 == 128) ? (tid & 7) : (tid & 15);
    const int r0 = 4 * a;
    const int c0 = (K2 == 128) ? ((tid >> 3) * 4) : ((tid >> 4) * 4);

    float acc[RT][4];
#pragma unroll
    for (int i = 0; i < RT; ++i)
#pragma unroll
        for (int j = 0; j < 4; ++j) acc[i][j] = 0.f;

    for (int p = 0; p < 4; ++p) {
        __syncthreads();
        for (int i = tid; i < 32 * K2 / 4; i += 256) {
            *reinterpret_cast<float4*>(&Ws[i * 4]) =
                *reinterpret_cast<const float4*>(&W[(size_t)p * 32 * K2 + (size_t)i * 4]);
        }
        __syncthreads();

#pragma unroll 4
        for (int kk = 0; kk < 32; ++kk) {
            const float* as = &As[(p * 32 + kk) * APAD];
            float4 av0 = *reinterpret_cast<const float4*>(as + r0);
            float4 wv = *reinterpret_cast<const float4*>(&Ws[kk * K2 + c0]);
            if (K2 == 128) {
                float4 av1 = *reinterpret_cast<const float4*>(as + r0 + 32);
#pragma unroll
                for (int j = 0; j < 4; ++j) {
                    float w = (&wv.x)[j];
                    acc[0][j] += av0.x * w;
                    acc[1][j] += av0.y * w;
                    acc[2][j] += av0.z * w;
                    acc[3][j] += av0.w * w;
                    acc[RT - 4][j] += av1.x * w;
                    acc[RT - 3][j] += av1.y * w;
                    acc[RT - 2][j] += av1.z * w;
                    acc[RT - 1][j] += av1.w * w;
                }
            } else {
#pragma unroll
                for (int j = 0; j < 4; ++j) {
                    float w = (&wv.x)[j];
                    acc[0][j] += av0.x * w;
                    acc[1][j] += av0.y * w;
                    acc[2][j] += av0.z * w;
                    acc[3][j] += av0.w * w;
                }
            }
        }
    }

#pragma unroll
    for (int i = 0; i < RT; ++i) {
        int rr = (i < 4) ? (r0 + i) : (r0 + 32 + (i - 4));
        int gr = row0 + rr;
        if (gr < n) {
            float4 o;
            o.x = acc[i][0]; o.y = acc[i][1]; o.z = acc[i][2]; o.w = acc[i][3];
            *reinterpret_cast<float4*>(&C[(size_t)gr * K2 + c0]) = o;
        }
    }
}

// one wave per dst node; 32 lanes x float4 cover a 128-col row -> the two
// wave-halves process 2 edges per VMEM; 2-deep manual unroll (4 rows in flight).
__global__ __launch_bounds__(256) void k_gather128(
    const int* __restrict__ off, const int* __restrict__ deg,
    const uint2* __restrict__ csr, const float* __restrict__ xw,
    const float* __restrict__ dinv, const float* __restrict__ b,
    float* __restrict__ agg, int n) {
    int wid = (blockIdx.x * blockDim.x + threadIdx.x) >> 6;
    int lane = threadIdx.x & 63;
    if (wid >= n) return;
    const int half = lane >> 5;
    const int c0 = (lane & 31) * 4;

    float a0 = 0.f, a1 = 0.f, a2 = 0.f, a3 = 0.f;
    const int s0 = off[wid];
    const int cnt = deg[wid] - 1;

    int t = half;
    for (; t + 2 < cnt; t += 4) {
        uint2 e0 = csr[s0 + t];
        uint2 e1 = csr[s0 + t + 2];
        float4 v0 = *reinterpret_cast<const float4*>(xw + (size_t)e0.x * 128 + c0);
        float4 v1 = *reinterpret_cast<const float4*>(xw + (size_t)e1.x * 128 + c0);
        float n0 = __uint_as_float(e0.y);
        float n1 = __uint_as_float(e1.y);
        a0 += n0 * v0.x; a1 += n0 * v0.y; a2 += n0 * v0.z; a3 += n0 * v0.w;
        a0 += n1 * v1.x; a1 += n1 * v1.y; a2 += n1 * v1.z; a3 += n1 * v1.w;
    }
    for (; t < cnt; t += 2) {
        uint2 e0 = csr[s0 + t];
        float4 v0 = *reinterpret_cast<const float4*>(xw + (size_t)e0.x * 128 + c0);
        float n0 = __uint_as_float(e0.y);
        a0 += n0 * v0.x; a1 += n0 * v0.y; a2 += n0 * v0.z; a3 += n0 * v0.w;
    }

    a0 += __shfl_xor(a0, 32);
    a1 += __shfl_xor(a1, 32);
    a2 += __shfl_xor(a2, 32);
    a3 += __shfl_xor(a3, 32);

    if (half == 0) {
        float di = dinv[wid];
        float dd = di * di;
        float4 sv = *reinterpret_cast<const float4*>(xw + (size_t)wid * 128 + c0);
        float4 bv = *reinterpret_cast<const float4*>(b + c0);
        float4 o;
        o.x = fmaxf(bv.x + dd * sv.x + a0, 0.f);
        o.y = fmaxf(bv.y + dd * sv.y + a1, 0.f);
        o.z = fmaxf(bv.z + dd * sv.z + a2, 0.f);
        o.w = fmaxf(bv.w + dd * sv.w + a3, 0.f);
        *reinterpret_cast<float4*>(agg + (size_t)wid * 128 + c0) = o;
    }
}

// one wave per dst node; 16 lanes x float4 cover a 64-col row -> 4 edges per
// VMEM via wave-quarters; log_softmax fused.
__global__ __launch_bounds__(256) void k_gather64_lsm(
    const int* __restrict__ off, const int* __restrict__ deg,
    const uint2* __restrict__ csr, const float* __restrict__ xw,
    const float* __restrict__ dinv, const float* __restrict__ b,
    float* __restrict__ out, int n) {
    int wid = (blockIdx.x * blockDim.x + threadIdx.x) >> 6;
    int lane = threadIdx.x & 63;
    if (wid >= n) return;
    const int q = lane >> 4;
    const int c0 = (lane & 15) * 4;

    float a0 = 0.f, a1 = 0.f, a2 = 0.f, a3 = 0.f;
    const int s0 = off[wid];
    const int cnt = deg[wid] - 1;

    int t = q;
    for (; t + 4 < cnt; t += 8) {
        uint2 e0 = csr[s0 + t];
        uint2 e1 = csr[s0 + t + 4];
        float4 v0 = *reinterpret_cast<const float4*>(xw + (size_t)e0.x * 64 + c0);
        float4 v1 = *reinterpret_cast<const float4*>(xw + (size_t)e1.x * 64 + c0);
        float n0 = __uint_as_float(e0.y);
        float n1 = __uint_as_float(e1.y);
        a0 += n0 * v0.x; a1 += n0 * v0.y; a2 += n0 * v0.z; a3 += n0 * v0.w;
        a0 += n1 * v1.x; a1 += n1 * v1.y; a2 += n1 * v1.z; a3 += n1 * v1.w;
    }
    for (; t < cnt; t += 4) {
        uint2 e0 = csr[s0 + t];
        float4 v0 = *reinterpret_cast<const float4*>(xw + (size_t)e0.x * 64 + c0);
        float n0 = __uint_as_float(e0.y);
        a0 += n0 * v0.x; a1 += n0 * v0.y; a2 += n0 * v0.z; a3 += n0 * v0.w;
    }

    // combine the 4 wave-quarters
    a0 += __shfl_xor(a0, 16); a0 += __shfl_xor(a0, 32);
    a1 += __shfl_xor(a1, 16); a1 += __shfl_xor(a1, 32);
    a2 += __shfl_xor(a2, 16); a2 += __shfl_xor(a2, 32);
    a3 += __shfl_xor(a3, 16); a3 += __shfl_xor(a3, 32);

    float di = dinv[wid];
    float dd = di * di;
    float4 sv = *reinterpret_cast<const float4*>(xw + (size_t)wid * 64 + c0);
    float4 bv = *reinterpret_cast<const float4*>(b + c0);
    float v0 = bv.x + dd * sv.x + a0;
    float v1 = bv.y + dd * sv.y + a1;
    float v2 = bv.z + dd * sv.z + a2;
    float v3 = bv.w + dd * sv.w + a3;

    float m = fmaxf(fmaxf(v0, v1), fmaxf(v2, v3));
#pragma unroll
    for (int o = 8; o; o >>= 1) m = fmaxf(m, __shfl_xor(m, o));
    float s = expf(v0 - m) + expf(v1 - m) + expf(v2 - m) + expf(v3 - m);
#pragma unroll
    for (int o = 8; o; o >>= 1) s += __shfl_xor(s, o);
    float ls = m + logf(s);

    if (lane < 16) {
        float4 o;
        o.x = v0 - ls; o.y = v1 - ls; o.z = v2 - ls; o.w = v3 - ls;
        *reinterpret_cast<float4*>(out + (size_t)wid * 64 + c0) = o;
    }
}

extern "C" void kernel_launch(void* const* d_in, const int* in_sizes, int n_in,
                              void* d_out, int out_size, void* d_ws, size_t ws_size,
                              hipStream_t stream) {
    const float* x  = (const float*)d_in[0];
    const int*   ei = (const int*)d_in[1];
    const float* W1 = (const float*)d_in[2];
    const float* b1 = (const float*)d_in[3];
    const float* W2 = (const float*)d_in[4];
    const float* b2 = (const float*)d_in[5];

    const int n = in_sizes[0] / K1;   // 50000
    const int e = in_sizes[1] / 2;    // 800000
    const int* src = ei;
    const int* dst = ei + e;
    float* out = (float*)d_out;

    const int nb_scan = (n + SCAN_B - 1) / SCAN_B;  // 196 for n=50000 (<=1024)

    // ws layout:
    // buf0[n*128] | buf1[n*128] | deg[n] | dinv[n] | off[n] | cur[n] |
    // blocksum[nb_scan] | (align 16) | csr[e] (uint2)
    float* buf0     = (float*)d_ws;
    float* buf1     = buf0 + (size_t)n * 128;
    int*   deg      = (int*)(buf1 + (size_t)n * 128);
    float* dinv     = (float*)(deg + n);
    int*   off      = (int*)(dinv + n);
    int*   cur      = off + n;
    int*   blocksum = cur + n;
    uint2* csr      = (uint2*)(((uintptr_t)(blocksum + nb_scan) + 15) & ~(uintptr_t)15);

    const int B = 256;

    k_init_deg<<<(n + B - 1) / B, B, 0, stream>>>(deg, n);
    k_count_deg<<<1024, B, 0, stream>>>(dst, e, deg);
    k_scan_part<<<nb_scan, SCAN_B, 0, stream>>>(deg, blocksum, n);
    k_scan_top<<<1, 1024, 0, stream>>>(blocksum, nb_scan);
    k_scan_final<<<nb_scan, SCAN_B, 0, stream>>>(deg, blocksum, off, cur, dinv, n);
    k_fill<<<1024, B, 0, stream>>>(src, dst, dinv, cur, csr, e);

    // layer 1: xw1 = x @ W1 ; agg1 = relu(gather)  -> buf1
    k_gemm<128><<<(n + 63) / 64, B, 0, stream>>>(x, W1, buf0, n);
    k_gather128<<<(n + 3) / 4, B, 0, stream>>>(off, deg, csr, buf0, dinv, b1, buf1, n);

    // layer 2: hw2 = agg1 @ W2 ; out = log_softmax(gather)
    k_gemm<64><<<(n + 63) / 64, B, 0, stream>>>(buf1, W2, buf0, n);
    k_gather64_lsm<<<(n + 3) / 4, B, 0, stream>>>(off, deg, csr, buf0, dinv, b2, out, n);
}

// Round 6
// 217.117 us; speedup vs baseline: 3.1979x; 1.1304x over previous
//
#include <hip/hip_runtime.h>

// ---------------------------------------------------------------------------
// 2-layer GCN, CSR-gather formulation, bf16 gather rows:
// out = log_softmax( Anorm @ relu(Anorm @ (x@W1) + b1) @ W2 + b2 )
// Anorm = D^-1/2 (A + I) D^-1/2, deg over destination nodes (incl. self loop)
// ---------------------------------------------------------------------------

constexpr int K1 = 128;
constexpr int SCAN_B = 256;

__device__ inline unsigned short f2b(float f) {  // f32 -> bf16 (round-nearest)
    unsigned u = __float_as_uint(f);
    u += 0x7fffu + ((u >> 16) & 1u);
    return (unsigned short)(u >> 16);
}

__global__ void k_init_deg(int* __restrict__ deg, int n) {
    int i = blockIdx.x * blockDim.x + threadIdx.x;
    if (i < n) deg[i] = 1;  // self loop
}

__global__ void k_count_deg(const int* __restrict__ dst, int e, int* __restrict__ deg) {
    int i = blockIdx.x * blockDim.x + threadIdx.x;
    int stride = gridDim.x * blockDim.x;
    for (; i < e; i += stride) atomicAdd(&deg[dst[i]], 1);
}

__global__ __launch_bounds__(SCAN_B) void k_scan_part(const int* __restrict__ deg,
                                                      int* __restrict__ blocksum, int n) {
    __shared__ int red[SCAN_B];
    int i = blockIdx.x * SCAN_B + threadIdx.x;
    int v = (i < n) ? deg[i] - 1 : 0;
    red[threadIdx.x] = v;
    __syncthreads();
    for (int o = SCAN_B / 2; o; o >>= 1) {
        if (threadIdx.x < o) red[threadIdx.x] += red[threadIdx.x + o];
        __syncthreads();
    }
    if (threadIdx.x == 0) blocksum[blockIdx.x] = red[0];
}

__global__ __launch_bounds__(1024) void k_scan_top(int* __restrict__ blocksum, int nb) {
    __shared__ int sh[1024];
    int t = threadIdx.x;
    int v = (t < nb) ? blocksum[t] : 0;
    sh[t] = v;
    __syncthreads();
    for (int o = 1; o < 1024; o <<= 1) {
        int u = (t >= o) ? sh[t - o] : 0;
        __syncthreads();
        sh[t] += u;
        __syncthreads();
    }
    if (t < nb) blocksum[t] = sh[t] - v;  // exclusive
}

__global__ __launch_bounds__(SCAN_B) void k_scan_final(const int* __restrict__ deg,
                                                       const int* __restrict__ blocksum,
                                                       int* __restrict__ off,
                                                       int* __restrict__ cur,
                                                       float* __restrict__ dinv, int n) {
    __shared__ int sh[SCAN_B];
    int t = threadIdx.x;
    int i = blockIdx.x * SCAN_B + t;
    int d = (i < n) ? deg[i] : 1;
    int v = (i < n) ? d - 1 : 0;
    sh[t] = v;
    __syncthreads();
    for (int o = 1; o < SCAN_B; o <<= 1) {
        int u = (t >= o) ? sh[t - o] : 0;
        __syncthreads();
        sh[t] += u;
        __syncthreads();
    }
    if (i < n) {
        int excl = blocksum[blockIdx.x] + sh[t] - v;
        off[i] = excl;
        cur[i] = excl;
        dinv[i] = rsqrtf((float)d);
    }
}

// counting-sort placement: interleaved csr entries {src, nrm} grouped by dst
__global__ void k_fill(const int* __restrict__ src, const int* __restrict__ dst,
                       const float* __restrict__ dinv, int* __restrict__ cur,
                       uint2* __restrict__ csr, int e) {
    int i = blockIdx.x * blockDim.x + threadIdx.x;
    int stride = gridDim.x * blockDim.x;
    for (; i < e; i += stride) {
        int s = src[i], d = dst[i];
        int p = atomicAdd(&cur[d], 1);
        uint2 ent;
        ent.x = (unsigned)s;
        ent.y = __float_as_uint(dinv[s] * dinv[d]);
        csr[p] = ent;
    }
}

// ---------------------------------------------------------------------------
// Register-blocked GEMM: Cb16[n,K2] = bf16( A[n,128] @ W[128,K2] )
// ---------------------------------------------------------------------------
template <int K2>
__global__ __launch_bounds__(256) void k_gemm(const float* __restrict__ A,
                                              const float* __restrict__ W,
                                              unsigned short* __restrict__ Cb, int n) {
    constexpr int BM = 64;
    constexpr int APAD = 68;
    constexpr int RT = (K2 == 128) ? 8 : 4;
    __shared__ float As[128 * APAD];
    __shared__ float Ws[32 * K2];

    const int tid = threadIdx.x;
    const int row0 = blockIdx.x * BM;

    {
        int r = tid >> 2;
        int gr = row0 + r;
        const float* Ar = A + (size_t)gr * 128;
        bool ok = gr < n;
#pragma unroll
        for (int j = 0; j < 8; ++j) {
            int q = (tid & 3) + 4 * j;
            float4 v = ok ? *reinterpret_cast<const float4*>(Ar + 4 * q)
                          : float4{0.f, 0.f, 0.f, 0.f};
            As[(4 * q + 0) * APAD + r] = v.x;
            As[(4 * q + 1) * APAD + r] = v.y;
            As[(4 * q + 2) * APAD + r] = v.z;
            As[(4 * q + 3) * APAD + r] = v.w;
        }
    }

    const int a = (K2 == 128) ? (tid & 7) : (tid & 15);
    const int r0 = 4 * a;
    const int c0 = (K2 == 128) ? ((tid >> 3) * 4) : ((tid >> 4) * 4);

    float acc[RT][4];
#pragma unroll
    for (int i = 0; i < RT; ++i)
#pragma unroll
        for (int j = 0; j < 4; ++j) acc[i][j] = 0.f;

    for (int p = 0; p < 4; ++p) {
        __syncthreads();
        for (int i = tid; i < 32 * K2 / 4; i += 256) {
            *reinterpret_cast<float4*>(&Ws[i * 4]) =
                *reinterpret_cast<const float4*>(&W[(size_t)p * 32 * K2 + (size_t)i * 4]);
        }
        __syncthreads();

#pragma unroll 4
        for (int kk = 0; kk < 32; ++kk) {
            const float* as = &As[(p * 32 + kk) * APAD];
            float4 av0 = *reinterpret_cast<const float4*>(as + r0);
            float4 wv = *reinterpret_cast<const float4*>(&Ws[kk * K2 + c0]);
            if (K2 == 128) {
                float4 av1 = *reinterpret_cast<const float4*>(as + r0 + 32);
#pragma unroll
                for (int j = 0; j < 4; ++j) {
                    float w = (&wv.x)[j];
                    acc[0][j] += av0.x * w;
                    acc[1][j] += av0.y * w;
                    acc[2][j] += av0.z * w;
                    acc[3][j] += av0.w * w;
                    acc[RT - 4][j] += av1.x * w;
                    acc[RT - 3][j] += av1.y * w;
                    acc[RT - 2][j] += av1.z * w;
                    acc[RT - 1][j] += av1.w * w;
                }
            } else {
#pragma unroll
                for (int j = 0; j < 4; ++j) {
                    float w = (&wv.x)[j];
                    acc[0][j] += av0.x * w;
                    acc[1][j] += av0.y * w;
                    acc[2][j] += av0.z * w;
                    acc[3][j] += av0.w * w;
                }
            }
        }
    }

#pragma unroll
    for (int i = 0; i < RT; ++i) {
        int rr = (i < 4) ? (r0 + i) : (r0 + 32 + (i - 4));
        int gr = row0 + rr;
        if (gr < n) {
            ushort4 o;
            o.x = f2b(acc[i][0]);
            o.y = f2b(acc[i][1]);
            o.z = f2b(acc[i][2]);
            o.w = f2b(acc[i][3]);
            *reinterpret_cast<ushort4*>(&Cb[(size_t)gr * K2 + c0]) = o;
        }
    }
}

// one wave per dst node. bf16 rows: quarter-wave (16 lanes x 8 bf16) covers a
// 128-col row -> 4 edges per VMEM pair, 2-deep unroll -> 8 rows in flight.
__global__ __launch_bounds__(256) void k_gather128(
    const int* __restrict__ off, const int* __restrict__ deg,
    const uint2* __restrict__ csr, const unsigned short* __restrict__ xb,
    const float* __restrict__ dinv, const float* __restrict__ b,
    float* __restrict__ agg, int n) {
    int wid = (blockIdx.x * blockDim.x + threadIdx.x) >> 6;
    int lane = threadIdx.x & 63;
    if (wid >= n) return;
    const int q = lane >> 4;        // quarter 0..3
    const int c0 = (lane & 15) * 8; // 8 cols per lane

    float a[8];
#pragma unroll
    for (int k = 0; k < 8; ++k) a[k] = 0.f;

    const int s0 = off[wid];
    const int cnt = deg[wid] - 1;

    int t = q;
    for (; t + 4 < cnt; t += 8) {
        uint2 e0 = csr[s0 + t];
        uint2 e1 = csr[s0 + t + 4];
        uint4 v0 = *reinterpret_cast<const uint4*>(xb + (size_t)e0.x * 128 + c0);
        uint4 v1 = *reinterpret_cast<const uint4*>(xb + (size_t)e1.x * 128 + c0);
        float n0 = __uint_as_float(e0.y);
        float n1 = __uint_as_float(e1.y);
#pragma unroll
        for (int j = 0; j < 4; ++j) {
            unsigned w0 = (&v0.x)[j];
            unsigned w1 = (&v1.x)[j];
            a[2 * j]     += n0 * __uint_as_float(w0 << 16);
            a[2 * j + 1] += n0 * __uint_as_float(w0 & 0xffff0000u);
            a[2 * j]     += n1 * __uint_as_float(w1 << 16);
            a[2 * j + 1] += n1 * __uint_as_float(w1 & 0xffff0000u);
        }
    }
    for (; t < cnt; t += 4) {
        uint2 e0 = csr[s0 + t];
        uint4 v0 = *reinterpret_cast<const uint4*>(xb + (size_t)e0.x * 128 + c0);
        float n0 = __uint_as_float(e0.y);
#pragma unroll
        for (int j = 0; j < 4; ++j) {
            unsigned w0 = (&v0.x)[j];
            a[2 * j]     += n0 * __uint_as_float(w0 << 16);
            a[2 * j + 1] += n0 * __uint_as_float(w0 & 0xffff0000u);
        }
    }

#pragma unroll
    for (int k = 0; k < 8; ++k) {
        a[k] += __shfl_xor(a[k], 16);
        a[k] += __shfl_xor(a[k], 32);
    }

    if (q == 0) {
        float di = dinv[wid];
        float dd = di * di;
        uint4 sv = *reinterpret_cast<const uint4*>(xb + (size_t)wid * 128 + c0);
        float4 bv0 = *reinterpret_cast<const float4*>(b + c0);
        float4 bv1 = *reinterpret_cast<const float4*>(b + c0 + 4);
        float o[8];
#pragma unroll
        for (int j = 0; j < 4; ++j) {
            unsigned w = (&sv.x)[j];
            o[2 * j]     = a[2 * j]     + dd * __uint_as_float(w << 16);
            o[2 * j + 1] = a[2 * j + 1] + dd * __uint_as_float(w & 0xffff0000u);
        }
        float4 r0, r1;
        r0.x = fmaxf(o[0] + bv0.x, 0.f);
        r0.y = fmaxf(o[1] + bv0.y, 0.f);
        r0.z = fmaxf(o[2] + bv0.z, 0.f);
        r0.w = fmaxf(o[3] + bv0.w, 0.f);
        r1.x = fmaxf(o[4] + bv1.x, 0.f);
        r1.y = fmaxf(o[5] + bv1.y, 0.f);
        r1.z = fmaxf(o[6] + bv1.z, 0.f);
        r1.w = fmaxf(o[7] + bv1.w, 0.f);
        *reinterpret_cast<float4*>(agg + (size_t)wid * 128 + c0) = r0;
        *reinterpret_cast<float4*>(agg + (size_t)wid * 128 + c0 + 4) = r1;
    }
}

// one wave per dst node. bf16 rows of 64 cols: eighth-wave (8 lanes x 8 bf16)
// covers a row -> 8 edges per VMEM pair; log_softmax fused.
__global__ __launch_bounds__(256) void k_gather64_lsm(
    const int* __restrict__ off, const int* __restrict__ deg,
    const uint2* __restrict__ csr, const unsigned short* __restrict__ hb,
    const float* __restrict__ dinv, const float* __restrict__ b,
    float* __restrict__ out, int n) {
    int wid = (blockIdx.x * blockDim.x + threadIdx.x) >> 6;
    int lane = threadIdx.x & 63;
    if (wid >= n) return;
    const int oct = lane >> 3;       // eighth 0..7
    const int c0 = (lane & 7) * 8;   // 8 cols per lane

    float a[8];
#pragma unroll
    for (int k = 0; k < 8; ++k) a[k] = 0.f;

    const int s0 = off[wid];
    const int cnt = deg[wid] - 1;

    int t = oct;
    for (; t + 8 < cnt; t += 16) {
        uint2 e0 = csr[s0 + t];
        uint2 e1 = csr[s0 + t + 8];
        uint4 v0 = *reinterpret_cast<const uint4*>(hb + (size_t)e0.x * 64 + c0);
        uint4 v1 = *reinterpret_cast<const uint4*>(hb + (size_t)e1.x * 64 + c0);
        float n0 = __uint_as_float(e0.y);
        float n1 = __uint_as_float(e1.y);
#pragma unroll
        for (int j = 0; j < 4; ++j) {
            unsigned w0 = (&v0.x)[j];
            unsigned w1 = (&v1.x)[j];
            a[2 * j]     += n0 * __uint_as_float(w0 << 16);
            a[2 * j + 1] += n0 * __uint_as_float(w0 & 0xffff0000u);
            a[2 * j]     += n1 * __uint_as_float(w1 << 16);
            a[2 * j + 1] += n1 * __uint_as_float(w1 & 0xffff0000u);
        }
    }
    for (; t < cnt; t += 8) {
        uint2 e0 = csr[s0 + t];
        uint4 v0 = *reinterpret_cast<const uint4*>(hb + (size_t)e0.x * 64 + c0);
        float n0 = __uint_as_float(e0.y);
#pragma unroll
        for (int j = 0; j < 4; ++j) {
            unsigned w0 = (&v0.x)[j];
            a[2 * j]     += n0 * __uint_as_float(w0 << 16);
            a[2 * j + 1] += n0 * __uint_as_float(w0 & 0xffff0000u);
        }
    }

#pragma unroll
    for (int k = 0; k < 8; ++k) {
        a[k] += __shfl_xor(a[k], 8);
        a[k] += __shfl_xor(a[k], 16);
        a[k] += __shfl_xor(a[k], 32);
    }

    // self loop + bias -> logits v[0..7] for cols c0..c0+7 (all lanes have them)
    float di = dinv[wid];
    float dd = di * di;
    uint4 sv = *reinterpret_cast<const uint4*>(hb + (size_t)wid * 64 + c0);
    float4 bv0 = *reinterpret_cast<const float4*>(b + c0);
    float4 bv1 = *reinterpret_cast<const float4*>(b + c0 + 4);
    float v[8];
#pragma unroll
    for (int j = 0; j < 4; ++j) {
        unsigned w = (&sv.x)[j];
        v[2 * j]     = a[2 * j]     + dd * __uint_as_float(w << 16);
        v[2 * j + 1] = a[2 * j + 1] + dd * __uint_as_float(w & 0xffff0000u);
    }
    v[0] += bv0.x; v[1] += bv0.y; v[2] += bv0.z; v[3] += bv0.w;
    v[4] += bv1.x; v[5] += bv1.y; v[6] += bv1.z; v[7] += bv1.w;

    float m = v[0];
#pragma unroll
    for (int k = 1; k < 8; ++k) m = fmaxf(m, v[k]);
    m = fmaxf(m, __shfl_xor(m, 1));
    m = fmaxf(m, __shfl_xor(m, 2));
    m = fmaxf(m, __shfl_xor(m, 4));

    float s = 0.f;
#pragma unroll
    for (int k = 0; k < 8; ++k) s += expf(v[k] - m);
    s += __shfl_xor(s, 1);
    s += __shfl_xor(s, 2);
    s += __shfl_xor(s, 4);
    float ls = m + logf(s);

    if (oct == 0) {
        float4 r0, r1;
        r0.x = v[0] - ls; r0.y = v[1] - ls; r0.z = v[2] - ls; r0.w = v[3] - ls;
        r1.x = v[4] - ls; r1.y = v[5] - ls; r1.z = v[6] - ls; r1.w = v[7] - ls;
        *reinterpret_cast<float4*>(out + (size_t)wid * 64 + c0) = r0;
        *reinterpret_cast<float4*>(out + (size_t)wid * 64 + c0 + 4) = r1;
    }
}

extern "C" void kernel_launch(void* const* d_in, const int* in_sizes, int n_in,
                              void* d_out, int out_size, void* d_ws, size_t ws_size,
                              hipStream_t stream) {
    const float* x  = (const float*)d_in[0];
    const int*   ei = (const int*)d_in[1];
    const float* W1 = (const float*)d_in[2];
    const float* b1 = (const float*)d_in[3];
    const float* W2 = (const float*)d_in[4];
    const float* b2 = (const float*)d_in[5];

    const int n = in_sizes[0] / K1;   // 50000
    const int e = in_sizes[1] / 2;    // 800000
    const int* src = ei;
    const int* dst = ei + e;
    float* out = (float*)d_out;

    const int nb_scan = (n + SCAN_B - 1) / SCAN_B;  // 196 (<=1024)

    // ws layout:
    // agg1[n*128] f32 | xb16[n*128] u16 | hb16[n*64] u16 | deg | dinv | off |
    // cur | blocksum | (align 16) | csr[e] uint2
    float*          agg1     = (float*)d_ws;
    unsigned short* xb16     = (unsigned short*)(agg1 + (size_t)n * 128);
    unsigned short* hb16     = xb16 + (size_t)n * 128;
    int*            deg      = (int*)(hb16 + (size_t)n * 64);
    float*          dinv     = (float*)(deg + n);
    int*            off      = (int*)(dinv + n);
    int*            cur      = off + n;
    int*            blocksum = cur + n;
    uint2*          csr      = (uint2*)(((uintptr_t)(blocksum + nb_scan) + 15) & ~(uintptr_t)15);

    const int B = 256;

    k_init_deg<<<(n + B - 1) / B, B, 0, stream>>>(deg, n);
    k_count_deg<<<1024, B, 0, stream>>>(dst, e, deg);
    k_scan_part<<<nb_scan, SCAN_B, 0, stream>>>(deg, blocksum, n);
    k_scan_top<<<1, 1024, 0, stream>>>(blocksum, nb_scan);
    k_scan_final<<<nb_scan, SCAN_B, 0, stream>>>(deg, blocksum, off, cur, dinv, n);
    k_fill<<<1024, B, 0, stream>>>(src, dst, dinv, cur, csr, e);

    // layer 1: xb16 = bf16(x @ W1) ; agg1 = relu(gather(xb16))
    k_gemm<128><<<(n + 63) / 64, B, 0, stream>>>(x, W1, xb16, n);
    k_gather128<<<(n + 3) / 4, B, 0, stream>>>(off, deg, csr, xb16, dinv, b1, agg1, n);

    // layer 2: hb16 = bf16(agg1 @ W2) ; out = log_softmax(gather(hb16))
    k_gemm<64><<<(n + 63) / 64, B, 0, stream>>>(agg1, W2, hb16, n);
    k_gather64_lsm<<<(n + 3) / 4, B, 0, stream>>>(off, deg, csr, hb16, dinv, b2, out, n);
}